// Round 5
// baseline (830.872 us; speedup 1.0000x reference)
//
#include <hip/hip_runtime.h>
#include <math.h>

#define N_NODES 200000
#define N_EDGES 6400000
#define F_IN    128
#define H_HID   6
#define C_OUT   10
#define G_BATCH 64

#define TILE_E     8192                                // edges per sort tile
#define NT         ((N_EDGES + TILE_E - 1) / TILE_E)   // 782 tiles
#define NBUCK      ((N_NODES + 1023) / 1024)           // 196 buckets of 1024 nodes
#define TOTAL_HIST (NBUCK * NT)                        // 153272
#define NSB        ((TOTAL_HIST + 255) / 256)          // 599 scan blocks
#define EPT        (TILE_E / 256)                      // 32 edges per thread

// ---- bf16 helpers (RNE) ---------------------------------------------------
__device__ __forceinline__ unsigned short f2bf(float f) {
    unsigned u = __float_as_uint(f);
    u += 0x7fff + ((u >> 16) & 1);
    return (unsigned short)(u >> 16);
}
__device__ __forceinline__ unsigned pack2(float a, float b) {
    return (unsigned)f2bf(a) | ((unsigned)f2bf(b) << 16);
}
__device__ __forceinline__ float bf_lo(unsigned u) { return __uint_as_float(u << 16); }
__device__ __forceinline__ float bf_hi(unsigned u) { return __uint_as_float(u & 0xffff0000u); }

// ---------------------------------------------------------------------------
// A1) per-tile histogram over destination buckets (col >> 10). LDS atomics only.
__global__ void histA_kernel(const int* __restrict__ col, int* __restrict__ tileHist, int E) {
    __shared__ int h[NBUCK];
    for (int i = threadIdx.x; i < NBUCK; i += 256) h[i] = 0;
    __syncthreads();
    int t = blockIdx.x;
    int base = t * TILE_E;
    for (int k = 0; k < TILE_E; k += 256) {
        int e = base + k + threadIdx.x;
        if (e < E) atomicAdd(&h[col[e] >> 10], 1);
    }
    __syncthreads();
    for (int b = threadIdx.x; b < NBUCK; b += 256) tileHist[b * NT + t] = h[b];
}

// A2) 3-phase exclusive scan over tileHist (bucket-major)
__global__ void scan_blocksum(const int* __restrict__ a, int* __restrict__ bsum, int n) {
    __shared__ int sm[256];
    int i = blockIdx.x * 256 + threadIdx.x;
    sm[threadIdx.x] = (i < n) ? a[i] : 0;
    __syncthreads();
    for (int s = 128; s > 0; s >>= 1) {
        if (threadIdx.x < s) sm[threadIdx.x] += sm[threadIdx.x + s];
        __syncthreads();
    }
    if (threadIdx.x == 0) bsum[blockIdx.x] = sm[0];
}

__global__ void scan_bsum(int* __restrict__ bsum, int nb) {
    int lane = threadIdx.x;   // block = 64
    int carry = 0;
    for (int base = 0; base < nb; base += 64) {
        int i = base + lane;
        int orig = (i < nb) ? bsum[i] : 0;
        int v = orig;
#pragma unroll
        for (int off = 1; off < 64; off <<= 1) {
            int t = __shfl_up(v, off);
            if (lane >= off) v += t;
        }
        int total = __shfl(v, 63);
        if (i < nb) bsum[i] = carry + v - orig;
        carry += total;
    }
}

__global__ void scan_final(int* __restrict__ a, const int* __restrict__ bsum, int n) {
    __shared__ int sm[256];
    int tid = threadIdx.x;
    int i = blockIdx.x * 256 + tid;
    int v = (i < n) ? a[i] : 0;
    sm[tid] = v;
    __syncthreads();
    for (int off = 1; off < 256; off <<= 1) {
        int t = (tid >= off) ? sm[tid - off] : 0;
        __syncthreads();
        sm[tid] += t;
        __syncthreads();
    }
    if (i < n) a[i] = sm[tid] - v + bsum[blockIdx.x];
}

// A3) scatter v2: LDS-sort the tile by bucket, then STREAMING writes per run.
//     Payload packed: (col&1023)<<18 | row.
__global__ __launch_bounds__(256) void scatterA_kernel(const int* __restrict__ row,
                                                       const int* __restrict__ col,
                                                       const int* __restrict__ scanned,
                                                       int* __restrict__ binned, int E) {
    __shared__ int sortbuf[TILE_E];   // 32 KB
    __shared__ int cnt[256];          // padded hist (196 used)
    __shared__ int pos[257];          // exclusive scan + total
    __shared__ int cur[256];
    __shared__ int lbase[NBUCK];
    int t = blockIdx.x, tid = threadIdx.x;
    int base = t * TILE_E;
    int tile_n = min(TILE_E, E - base);

    cnt[tid] = 0;
    if (tid < NBUCK) lbase[tid] = scanned[tid * NT + t];
    __syncthreads();

    // phase 0: read edges into registers, LDS histogram
    int myval[EPT];
#pragma unroll
    for (int k = 0; k < EPT; ++k) {
        int e = base + k * 256 + tid;
        if (e < E) {
            int c = col[e];
            myval[k] = ((c & 1023) << 18) | row[e];
            atomicAdd(&cnt[c >> 10], 1);
        }
    }
    __syncthreads();

    // phase 1: exclusive scan of cnt -> pos, init cursors
    int v = cnt[tid];
    pos[tid] = v;
    __syncthreads();
    for (int off = 1; off < 256; off <<= 1) {
        int tv = (tid >= off) ? pos[tid - off] : 0;
        __syncthreads();
        pos[tid] += tv;
        __syncthreads();
    }
    int incl = pos[tid];
    __syncthreads();
    pos[tid] = incl - v;
    cur[tid] = incl - v;
    if (tid == 255) pos[256] = incl;
    __syncthreads();

    // phase 2: place into LDS sort buffer (col re-read is L1/L2-hot)
#pragma unroll
    for (int k = 0; k < EPT; ++k) {
        int e = base + k * 256 + tid;
        if (e < E) {
            int b = col[e] >> 10;
            int p = atomicAdd(&cur[b], 1);
            sortbuf[p] = myval[k];
        }
    }
    __syncthreads();

    // phase 3: streaming write-out; position -> bucket via LDS binary search
    for (int i = tid; i < tile_n; i += 256) {
        int lo = 0, hi = NBUCK - 1;
        while (lo < hi) {
            int mid = (lo + hi + 1) >> 1;
            if (pos[mid] <= i) lo = mid; else hi = mid - 1;
        }
        binned[lbase[lo] + (i - pos[lo])] = sortbuf[i];
    }
}

// B) per-bucket degree count -> dis
__global__ __launch_bounds__(1024) void degC_kernel(const int* __restrict__ scanned,
                                                    const int* __restrict__ binned,
                                                    float* __restrict__ dis, int E) {
    __shared__ int cnt[1024];
    int b = blockIdx.x, tid = threadIdx.x;
    int bb = scanned[b * NT];
    int be = (b + 1 < NBUCK) ? scanned[(b + 1) * NT] : E;
    cnt[tid] = 0;
    __syncthreads();
    for (int e = bb + tid; e < be; e += 1024)
        atomicAdd(&cnt[binned[e] >> 18], 1);
    __syncthreads();
    int n = (b << 10) + tid;
    if (n < N_NODES) dis[n] = rsqrtf((float)cnt[tid] + 1.0f);
}

// ---------------------------------------------------------------------------
// xw1: h1b row (uint4) = { bf16(d*a0,d*a1), bf16(d*a2,d*a3), bf16(d*a4,d*a5), bits(d) }
__global__ void xw1_kernel(const float* __restrict__ x, const float* __restrict__ W1,
                           const float* __restrict__ dis, uint4* __restrict__ h1b) {
    __shared__ float w[F_IN * H_HID];
    for (int i = threadIdx.x; i < F_IN * H_HID; i += blockDim.x) w[i] = W1[i];
    __syncthreads();
    int n = blockIdx.x * blockDim.x + threadIdx.x;
    if (n >= N_NODES) return;
    float acc[H_HID] = {0.f, 0.f, 0.f, 0.f, 0.f, 0.f};
    const float4* xr = (const float4*)(x + (size_t)n * F_IN);
#pragma unroll 4
    for (int f4 = 0; f4 < F_IN / 4; ++f4) {
        float4 v = xr[f4];
        int f = f4 * 4;
#pragma unroll
        for (int j = 0; j < H_HID; ++j) {
            acc[j] += v.x * w[(f + 0) * H_HID + j] + v.y * w[(f + 1) * H_HID + j]
                    + v.z * w[(f + 2) * H_HID + j] + v.w * w[(f + 3) * H_HID + j];
        }
    }
    float d = dis[n];
    uint4 o;
    o.x = pack2(d * acc[0], d * acc[1]);
    o.y = pack2(d * acc[2], d * acc[3]);
    o.z = pack2(d * acc[4], d * acc[5]);
    o.w = __float_as_uint(d);
    h1b[n] = o;
}

// layer1: block per bucket. Stream binned run, gather h1b[row], LDS f32 atomics
// into acc[1024][7] (stride 7 = full bank spread). Epilogue: relu + pre-scale.
__global__ __launch_bounds__(1024) void layer1_kernel(const int* __restrict__ scanned,
                                                      const int* __restrict__ binned,
                                                      const uint4* __restrict__ h1b,
                                                      const float* __restrict__ b1,
                                                      uint4* __restrict__ rs, int E) {
    __shared__ float acc[1024 * 7];   // 28 KB
    int b = blockIdx.x, tid = threadIdx.x;
    int bb = scanned[b * NT];
    int be = (b + 1 < NBUCK) ? scanned[(b + 1) * NT] : E;
#pragma unroll
    for (int k = 0; k < 7; ++k) acc[tid + k * 1024] = 0.f;
    __syncthreads();
    for (int e = bb + tid; e < be; e += 1024) {
        int p = binned[e];
        uint4 v = h1b[p & 0x3FFFF];
        float* a = &acc[(p >> 18) * 7];
        atomicAdd(a + 0, bf_lo(v.x)); atomicAdd(a + 1, bf_hi(v.x));
        atomicAdd(a + 2, bf_lo(v.y)); atomicAdd(a + 3, bf_hi(v.y));
        atomicAdd(a + 4, bf_lo(v.z)); atomicAdd(a + 5, bf_hi(v.z));
    }
    __syncthreads();
    int n = (b << 10) + tid;
    if (n >= N_NODES) return;
    uint4 self = h1b[n];
    float d = __uint_as_float(self.w);
    float sf[H_HID] = {bf_lo(self.x), bf_hi(self.x), bf_lo(self.y),
                       bf_hi(self.y), bf_lo(self.z), bf_hi(self.z)};
    float* a = &acc[tid * 7];
    float r[H_HID];
#pragma unroll
    for (int j = 0; j < H_HID; ++j) {
        float v = d * (a[j] + sf[j]) + b1[j];
        r[j] = d * (v > 0.f ? v : 0.f);   // pre-scaled for layer 2
    }
    uint4 o;
    o.x = pack2(r[0], r[1]);
    o.y = pack2(r[2], r[3]);
    o.z = pack2(r[4], r[5]);
    o.w = self.w;
    rs[n] = o;
}

// layer2: same aggregation structure (6ch), then W2 post-aggregation + pooling.
__global__ __launch_bounds__(1024) void layer2_pool_kernel(const int* __restrict__ scanned,
                                                           const int* __restrict__ binned,
                                                           const uint4* __restrict__ rs,
                                                           const float* __restrict__ W2,
                                                           const int* __restrict__ batch,
                                                           float* __restrict__ sums, int E) {
    __shared__ float acc[1024 * 7];
    __shared__ float w2s[H_HID * C_OUT];
    int b = blockIdx.x, tid = threadIdx.x;
    if (tid < H_HID * C_OUT) w2s[tid] = W2[tid];
    int bb = scanned[b * NT];
    int be = (b + 1 < NBUCK) ? scanned[(b + 1) * NT] : E;
#pragma unroll
    for (int k = 0; k < 7; ++k) acc[tid + k * 1024] = 0.f;
    __syncthreads();
    for (int e = bb + tid; e < be; e += 1024) {
        int p = binned[e];
        uint4 v = rs[p & 0x3FFFF];
        float* a = &acc[(p >> 18) * 7];
        atomicAdd(a + 0, bf_lo(v.x)); atomicAdd(a + 1, bf_hi(v.x));
        atomicAdd(a + 2, bf_lo(v.y)); atomicAdd(a + 3, bf_hi(v.y));
        atomicAdd(a + 4, bf_lo(v.z)); atomicAdd(a + 5, bf_hi(v.z));
    }
    __syncthreads();
    int n = (b << 10) + tid;
    if (n >= N_NODES) return;   // whole trailing waves only (320 % 64 == 0)
    uint4 self = rs[n];
    float d = __uint_as_float(self.w);
    float* a = &acc[tid * 7];
    float t6[H_HID] = {a[0] + bf_lo(self.x), a[1] + bf_hi(self.x), a[2] + bf_lo(self.y),
                       a[3] + bf_hi(self.y), a[4] + bf_lo(self.z), a[5] + bf_hi(self.z)};
    float val[C_OUT];
#pragma unroll
    for (int c = 0; c < C_OUT; ++c) {
        float s = 0.f;
#pragma unroll
        for (int j = 0; j < H_HID; ++j) s += t6[j] * w2s[j * C_OUT + c];
        val[c] = d * s;
    }
    int g = batch[n];
    int g0 = __shfl(g, 0);
    unsigned long long ball = __ballot(g == g0);
    if (ball == 0xFFFFFFFFFFFFFFFFULL) {
#pragma unroll
        for (int c = 0; c < C_OUT; ++c)
#pragma unroll
            for (int off = 32; off > 0; off >>= 1) val[c] += __shfl_xor(val[c], off);
        int lane = tid & 63;
        if (lane < C_OUT) atomicAdd(&sums[g0 * C_OUT + lane], val[lane]);
    } else {
#pragma unroll
        for (int c = 0; c < C_OUT; ++c) atomicAdd(&sums[g * C_OUT + c], val[c]);
    }
}

// mean (counts via binary search on sorted batch) + b2 + log_softmax
__global__ void pool_finish_kernel(const float* __restrict__ sums, const int* __restrict__ batch,
                                   const float* __restrict__ b2, float* __restrict__ out) {
    int g = threadIdx.x;
    if (g >= G_BATCH) return;
    int lo = 0, hi = N_NODES;
    while (lo < hi) { int mid = (lo + hi) >> 1; if (batch[mid] < g) lo = mid + 1; else hi = mid; }
    int c0 = lo;
    hi = N_NODES;
    while (lo < hi) { int mid = (lo + hi) >> 1; if (batch[mid] < g + 1) lo = mid + 1; else hi = mid; }
    float inv = 1.0f / fmaxf((float)(lo - c0), 1.0f);
    float v[C_OUT], m = -INFINITY;
#pragma unroll
    for (int c = 0; c < C_OUT; ++c) {
        v[c] = sums[g * C_OUT + c] * inv + b2[c];
        m = fmaxf(m, v[c]);
    }
    float s = 0.f;
#pragma unroll
    for (int c = 0; c < C_OUT; ++c) s += expf(v[c] - m);
    float lse = m + logf(s);
#pragma unroll
    for (int c = 0; c < C_OUT; ++c) out[g * C_OUT + c] = v[c] - lse;
}

extern "C" void kernel_launch(void* const* d_in, const int* in_sizes, int n_in,
                              void* d_out, int out_size, void* d_ws, size_t ws_size,
                              hipStream_t stream) {
    const float* x   = (const float*)d_in[0];
    const int* ei    = (const int*)d_in[1];
    const int* row   = ei;
    const int* col   = ei + N_EDGES;
    const int* batch = (const int*)d_in[2];
    const float* W1  = (const float*)d_in[3];
    const float* b1  = (const float*)d_in[4];
    const float* W2  = (const float*)d_in[5];
    const float* b2  = (const float*)d_in[6];
    float* out = (float*)d_out;

    // workspace layout — region sizes multiples of 16 B so uint4 arrays stay aligned
    char* p = (char*)d_ws;
    float* sums     = (float*)p;  p += (size_t)G_BATCH * C_OUT * 4;      // [zero] 2560B
    int*   tileHist = (int*)p;    p += (size_t)TOTAL_HIST * 4;           // 613088B
    int*   bsum     = (int*)p;    p += (size_t)(NSB + 1) * 4;            // 2400B
    float* dis      = (float*)p;  p += (size_t)N_NODES * 4;              // 800000B
    int*   binned   = (int*)p;    p += (size_t)N_EDGES * 4;              // 25.6MB (persistent)
    uint4* h1b      = (uint4*)p;  p += (size_t)N_NODES * 16;             // 3.2MB
    uint4* rs       = (uint4*)p;  p += (size_t)N_NODES * 16;             // 3.2MB

    hipMemsetAsync(sums, 0, (size_t)G_BATCH * C_OUT * 4, stream);

    histA_kernel   <<<NT, 256, 0, stream>>>(col, tileHist, N_EDGES);
    scan_blocksum  <<<NSB, 256, 0, stream>>>(tileHist, bsum, TOTAL_HIST);
    scan_bsum      <<<1, 64, 0, stream>>>(bsum, NSB);
    scan_final     <<<NSB, 256, 0, stream>>>(tileHist, bsum, TOTAL_HIST);
    scatterA_kernel<<<NT, 256, 0, stream>>>(row, col, tileHist, binned, N_EDGES);
    degC_kernel    <<<NBUCK, 1024, 0, stream>>>(tileHist, binned, dis, N_EDGES);
    xw1_kernel     <<<(N_NODES + 255) / 256, 256, 0, stream>>>(x, W1, dis, h1b);
    layer1_kernel  <<<NBUCK, 1024, 0, stream>>>(tileHist, binned, h1b, b1, rs, N_EDGES);
    layer2_pool_kernel<<<NBUCK, 1024, 0, stream>>>(tileHist, binned, rs, W2, batch, sums, N_EDGES);
    pool_finish_kernel<<<1, 64, 0, stream>>>(sums, batch, b2, out);
}

// Round 6
// 451.251 us; speedup vs baseline: 1.8413x; 1.8413x over previous
//
#include <hip/hip_runtime.h>
#include <math.h>

#define N_NODES 200000
#define N_EDGES 6400000
#define F_IN    128
#define H_HID   6
#define C_OUT   10
#define G_BATCH 64

#define TILE_E     8192                                // edges per sort tile
#define NT         ((N_EDGES + TILE_E - 1) / TILE_E)   // 782 tiles
#define NBUCK      ((N_NODES + 1023) / 1024)           // 196 buckets of 1024 nodes
#define TOTAL_HIST (NBUCK * NT)                        // 153272
#define NSB        ((TOTAL_HIST + 255) / 256)          // 599 scan blocks
#define EPT        (TILE_E / 256)                      // 32 edges per thread

// ---- bf16 helpers (RNE) ---------------------------------------------------
__device__ __forceinline__ unsigned short f2bf(float f) {
    unsigned u = __float_as_uint(f);
    u += 0x7fff + ((u >> 16) & 1);
    return (unsigned short)(u >> 16);
}
__device__ __forceinline__ unsigned pack2(float a, float b) {
    return (unsigned)f2bf(a) | ((unsigned)f2bf(b) << 16);
}
__device__ __forceinline__ float bf_lo(unsigned u) { return __uint_as_float(u << 16); }
__device__ __forceinline__ float bf_hi(unsigned u) { return __uint_as_float(u & 0xffff0000u); }

// ---------------------------------------------------------------------------
// A1) per-tile histogram over destination buckets (col >> 10). LDS atomics only.
__global__ void histA_kernel(const int* __restrict__ col, int* __restrict__ tileHist, int E) {
    __shared__ int h[NBUCK];
    for (int i = threadIdx.x; i < NBUCK; i += 256) h[i] = 0;
    __syncthreads();
    int t = blockIdx.x;
    int base = t * TILE_E;
    for (int k = 0; k < TILE_E; k += 256) {
        int e = base + k + threadIdx.x;
        if (e < E) atomicAdd(&h[col[e] >> 10], 1);
    }
    __syncthreads();
    for (int b = threadIdx.x; b < NBUCK; b += 256) tileHist[b * NT + t] = h[b];
}

// A2) 3-phase exclusive scan over tileHist (bucket-major)
__global__ void scan_blocksum(const int* __restrict__ a, int* __restrict__ bsum, int n) {
    __shared__ int sm[256];
    int i = blockIdx.x * 256 + threadIdx.x;
    sm[threadIdx.x] = (i < n) ? a[i] : 0;
    __syncthreads();
    for (int s = 128; s > 0; s >>= 1) {
        if (threadIdx.x < s) sm[threadIdx.x] += sm[threadIdx.x + s];
        __syncthreads();
    }
    if (threadIdx.x == 0) bsum[blockIdx.x] = sm[0];
}

__global__ void scan_bsum(int* __restrict__ bsum, int nb) {
    int lane = threadIdx.x;   // block = 64
    int carry = 0;
    for (int base = 0; base < nb; base += 64) {
        int i = base + lane;
        int orig = (i < nb) ? bsum[i] : 0;
        int v = orig;
#pragma unroll
        for (int off = 1; off < 64; off <<= 1) {
            int t = __shfl_up(v, off);
            if (lane >= off) v += t;
        }
        int total = __shfl(v, 63);
        if (i < nb) bsum[i] = carry + v - orig;
        carry += total;
    }
}

__global__ void scan_final(int* __restrict__ a, const int* __restrict__ bsum, int n) {
    __shared__ int sm[256];
    int tid = threadIdx.x;
    int i = blockIdx.x * 256 + tid;
    int v = (i < n) ? a[i] : 0;
    sm[tid] = v;
    __syncthreads();
    for (int off = 1; off < 256; off <<= 1) {
        int t = (tid >= off) ? sm[tid - off] : 0;
        __syncthreads();
        sm[tid] += t;
        __syncthreads();
    }
    if (i < n) a[i] = sm[tid] - v + bsum[blockIdx.x];
}

// A3) scatter v2 (validated R4): LDS-sort the tile by bucket, then STREAMING
//     writes per run. Payload packed: (col&1023)<<18 | row.
__global__ __launch_bounds__(256) void scatterA_kernel(const int* __restrict__ row,
                                                       const int* __restrict__ col,
                                                       const int* __restrict__ scanned,
                                                       int* __restrict__ binned, int E) {
    __shared__ int sortbuf[TILE_E];   // 32 KB
    __shared__ int cnt[256];
    __shared__ int pos[257];
    __shared__ int cur[256];
    __shared__ int lbase[NBUCK];
    int t = blockIdx.x, tid = threadIdx.x;
    int base = t * TILE_E;
    int tile_n = min(TILE_E, E - base);

    cnt[tid] = 0;
    if (tid < NBUCK) lbase[tid] = scanned[tid * NT + t];
    __syncthreads();

    int myval[EPT];
#pragma unroll
    for (int k = 0; k < EPT; ++k) {
        int e = base + k * 256 + tid;
        if (e < E) {
            int c = col[e];
            myval[k] = ((c & 1023) << 18) | row[e];
            atomicAdd(&cnt[c >> 10], 1);
        }
    }
    __syncthreads();

    int v = cnt[tid];
    pos[tid] = v;
    __syncthreads();
    for (int off = 1; off < 256; off <<= 1) {
        int tv = (tid >= off) ? pos[tid - off] : 0;
        __syncthreads();
        pos[tid] += tv;
        __syncthreads();
    }
    int incl = pos[tid];
    __syncthreads();
    pos[tid] = incl - v;
    cur[tid] = incl - v;
    if (tid == 255) pos[256] = incl;
    __syncthreads();

#pragma unroll
    for (int k = 0; k < EPT; ++k) {
        int e = base + k * 256 + tid;
        if (e < E) {
            int b = col[e] >> 10;
            int p = atomicAdd(&cur[b], 1);
            sortbuf[p] = myval[k];
        }
    }
    __syncthreads();

    for (int i = tid; i < tile_n; i += 256) {
        int lo = 0, hi = NBUCK - 1;
        while (lo < hi) {
            int mid = (lo + hi + 1) >> 1;
            if (pos[mid] <= i) lo = mid; else hi = mid - 1;
        }
        binned[lbase[lo] + (i - pos[lo])] = sortbuf[i];
    }
}

// B) per-bucket CSR: LDS count -> block scan -> offs/dis -> LDS-cursor placement
__global__ __launch_bounds__(1024) void passB_kernel(const int* __restrict__ scanned,
                                                     const int* __restrict__ binned,
                                                     int* __restrict__ offs, float* __restrict__ dis,
                                                     int* __restrict__ csr, int E) {
    __shared__ int cnt[1024];
    __shared__ int scn[1024];
    __shared__ int cur[1024];
    int b = blockIdx.x, tid = threadIdx.x;
    int bb = scanned[b * NT];
    int be = (b + 1 < NBUCK) ? scanned[(b + 1) * NT] : E;
    cnt[tid] = 0; cur[tid] = 0;
    __syncthreads();
    for (int e = bb + tid; e < be; e += 1024)
        atomicAdd(&cnt[binned[e] >> 18], 1);
    __syncthreads();
    int v = cnt[tid];
    scn[tid] = v;
    __syncthreads();
    for (int off = 1; off < 1024; off <<= 1) {
        int t2 = (tid >= off) ? scn[tid - off] : 0;
        __syncthreads();
        scn[tid] += t2;
        __syncthreads();
    }
    int excl = scn[tid] - v;
    scn[tid] = excl;
    int n = (b << 10) + tid;
    if (n < N_NODES) {
        offs[n] = bb + excl;
        dis[n] = rsqrtf((float)v + 1.0f);
    }
    if (b == NBUCK - 1 && tid == 0) offs[N_NODES] = E;
    __syncthreads();
    for (int e = bb + tid; e < be; e += 1024) {
        int p = binned[e];
        int local = p >> 18;
        int pos = atomicAdd(&cur[local], 1);
        csr[bb + scn[local] + pos] = p & 0x3FFFF;
    }
}

// ---------------------------------------------------------------------------
// xw1: h1b row (uint4) = { bf16(d*a0,d*a1), bf16(d*a2,d*a3), bf16(d*a4,d*a5), bits(d) }
__global__ void xw1_kernel(const float* __restrict__ x, const float* __restrict__ W1,
                           const float* __restrict__ dis, uint4* __restrict__ h1b) {
    __shared__ float w[F_IN * H_HID];
    for (int i = threadIdx.x; i < F_IN * H_HID; i += blockDim.x) w[i] = W1[i];
    __syncthreads();
    int n = blockIdx.x * blockDim.x + threadIdx.x;
    if (n >= N_NODES) return;
    float acc[H_HID] = {0.f, 0.f, 0.f, 0.f, 0.f, 0.f};
    const float4* xr = (const float4*)(x + (size_t)n * F_IN);
#pragma unroll 4
    for (int f4 = 0; f4 < F_IN / 4; ++f4) {
        float4 v = xr[f4];
        int f = f4 * 4;
#pragma unroll
        for (int j = 0; j < H_HID; ++j) {
            acc[j] += v.x * w[(f + 0) * H_HID + j] + v.y * w[(f + 1) * H_HID + j]
                    + v.z * w[(f + 2) * H_HID + j] + v.w * w[(f + 3) * H_HID + j];
        }
    }
    float d = dis[n];
    uint4 o;
    o.x = pack2(d * acc[0], d * acc[1]);
    o.y = pack2(d * acc[2], d * acc[3]);
    o.z = pack2(d * acc[4], d * acc[5]);
    o.w = __float_as_uint(d);
    h1b[n] = o;
}

// gather conv1: 16 lanes per node. One uint4 gather per edge (L2-resident 3.2MB).
__global__ void gather1_kernel(const int* __restrict__ offs, const int* __restrict__ csr,
                               const uint4* __restrict__ h1b, const float* __restrict__ b1,
                               uint4* __restrict__ rs) {
    int grp = threadIdx.x >> 4, sub = threadIdx.x & 15;
    int n = blockIdx.x * 16 + grp;
    int s = offs[n], e_end = offs[n + 1];
    float a[H_HID] = {0.f, 0.f, 0.f, 0.f, 0.f, 0.f};
    for (int e = s + sub; e < e_end; e += 16) {
        uint4 v = h1b[csr[e]];
        a[0] += bf_lo(v.x); a[1] += bf_hi(v.x);
        a[2] += bf_lo(v.y); a[3] += bf_hi(v.y);
        a[4] += bf_lo(v.z); a[5] += bf_hi(v.z);
    }
#pragma unroll
    for (int j = 0; j < H_HID; ++j)
#pragma unroll
        for (int off = 8; off > 0; off >>= 1) a[j] += __shfl_xor(a[j], off);
    uint4 self = h1b[n];
    float d = __uint_as_float(self.w);
    float sf[H_HID] = {bf_lo(self.x), bf_hi(self.x), bf_lo(self.y),
                       bf_hi(self.y), bf_lo(self.z), bf_hi(self.z)};
    float r[H_HID];
#pragma unroll
    for (int j = 0; j < H_HID; ++j) {
        float v = d * (a[j] + sf[j]) + b1[j];
        r[j] = d * (v > 0.f ? v : 0.f);    // pre-scaled for layer 2
    }
    if (sub == 0) {
        uint4 o;
        o.x = pack2(r[0], r[1]);
        o.y = pack2(r[2], r[3]);
        o.z = pack2(r[4], r[5]);
        o.w = self.w;
        rs[n] = o;
    }
}

// gather conv2 (6ch) + W2 post-aggregation + fused pooling. 16 lanes per node.
__global__ void gather2_pool_kernel(const int* __restrict__ offs, const int* __restrict__ csr,
                                    const uint4* __restrict__ rs, const float* __restrict__ W2,
                                    const int* __restrict__ batch, float* __restrict__ sums) {
    __shared__ float w2s[H_HID * C_OUT];
    __shared__ float nodeval[16][C_OUT];
    __shared__ int lg[16];
    if (threadIdx.x < H_HID * C_OUT) w2s[threadIdx.x] = W2[threadIdx.x];
    __syncthreads();
    int grp = threadIdx.x >> 4, sub = threadIdx.x & 15;
    int n = blockIdx.x * 16 + grp;
    int s = offs[n], e_end = offs[n + 1];
    float a[H_HID] = {0.f, 0.f, 0.f, 0.f, 0.f, 0.f};
    for (int e = s + sub; e < e_end; e += 16) {
        uint4 v = rs[csr[e]];
        a[0] += bf_lo(v.x); a[1] += bf_hi(v.x);
        a[2] += bf_lo(v.y); a[3] += bf_hi(v.y);
        a[4] += bf_lo(v.z); a[5] += bf_hi(v.z);
    }
#pragma unroll
    for (int j = 0; j < H_HID; ++j)
#pragma unroll
        for (int off = 8; off > 0; off >>= 1) a[j] += __shfl_xor(a[j], off);
    uint4 self = rs[n];
    float d = __uint_as_float(self.w);
    float t[H_HID] = {a[0] + bf_lo(self.x), a[1] + bf_hi(self.x), a[2] + bf_lo(self.y),
                      a[3] + bf_hi(self.y), a[4] + bf_lo(self.z), a[5] + bf_hi(self.z)};
    if (sub < C_OUT) {
        float acc = 0.f;
#pragma unroll
        for (int j = 0; j < H_HID; ++j) acc += t[j] * w2s[j * C_OUT + sub];
        nodeval[grp][sub] = d * acc;
    }
    if (sub == 0) lg[grp] = batch[n];
    __syncthreads();
    if (threadIdx.x < C_OUT) {
        int c = threadIdx.x;
        float acc = 0.f;
        int gcur = lg[0];
#pragma unroll
        for (int w = 0; w < 16; ++w) {
            if (lg[w] != gcur) {
                atomicAdd(&sums[gcur * C_OUT + c], acc);
                gcur = lg[w]; acc = 0.f;
            }
            acc += nodeval[w][c];
        }
        atomicAdd(&sums[gcur * C_OUT + c], acc);
    }
}

// mean (counts via binary search on sorted batch) + b2 + log_softmax
__global__ void pool_finish_kernel(const float* __restrict__ sums, const int* __restrict__ batch,
                                   const float* __restrict__ b2, float* __restrict__ out) {
    int g = threadIdx.x;
    if (g >= G_BATCH) return;
    int lo = 0, hi = N_NODES;
    while (lo < hi) { int mid = (lo + hi) >> 1; if (batch[mid] < g) lo = mid + 1; else hi = mid; }
    int c0 = lo;
    hi = N_NODES;
    while (lo < hi) { int mid = (lo + hi) >> 1; if (batch[mid] < g + 1) lo = mid + 1; else hi = mid; }
    float inv = 1.0f / fmaxf((float)(lo - c0), 1.0f);
    float v[C_OUT], m = -INFINITY;
#pragma unroll
    for (int c = 0; c < C_OUT; ++c) {
        v[c] = sums[g * C_OUT + c] * inv + b2[c];
        m = fmaxf(m, v[c]);
    }
    float s = 0.f;
#pragma unroll
    for (int c = 0; c < C_OUT; ++c) s += expf(v[c] - m);
    float lse = m + logf(s);
#pragma unroll
    for (int c = 0; c < C_OUT; ++c) out[g * C_OUT + c] = v[c] - lse;
}

extern "C" void kernel_launch(void* const* d_in, const int* in_sizes, int n_in,
                              void* d_out, int out_size, void* d_ws, size_t ws_size,
                              hipStream_t stream) {
    const float* x   = (const float*)d_in[0];
    const int* ei    = (const int*)d_in[1];
    const int* row   = ei;
    const int* col   = ei + N_EDGES;
    const int* batch = (const int*)d_in[2];
    const float* W1  = (const float*)d_in[3];
    const float* b1  = (const float*)d_in[4];
    const float* W2  = (const float*)d_in[5];
    const float* b2  = (const float*)d_in[6];
    float* out = (float*)d_out;

    // workspace layout — every region size a multiple of 16 B so uint4 arrays stay aligned
    char* p = (char*)d_ws;
    float* sums     = (float*)p;  p += (size_t)G_BATCH * C_OUT * 4;      // [zero] 2560B
    int*   tileHist = (int*)p;    p += (size_t)TOTAL_HIST * 4;           // 613088B
    int*   bsum     = (int*)p;    p += (size_t)(NSB + 1) * 4;            // 2400B
    int*   offs     = (int*)p;    p += (size_t)(N_NODES + 4) * 4;        // 800016B
    float* dis      = (float*)p;  p += (size_t)N_NODES * 4;              // 800000B
    int*   csr      = (int*)p;    p += (size_t)N_EDGES * 4;              // 25.6MB
    int*   binned   = (int*)p;                                           // 25.6MB, dead after passB
    uint4* h1b      = (uint4*)binned;                                    // 3.2MB, aliases binned
    uint4* rs       = (uint4*)binned + N_NODES;                          // 3.2MB

    hipMemsetAsync(sums, 0, (size_t)G_BATCH * C_OUT * 4, stream);

    histA_kernel   <<<NT, 256, 0, stream>>>(col, tileHist, N_EDGES);
    scan_blocksum  <<<NSB, 256, 0, stream>>>(tileHist, bsum, TOTAL_HIST);
    scan_bsum      <<<1, 64, 0, stream>>>(bsum, NSB);
    scan_final     <<<NSB, 256, 0, stream>>>(tileHist, bsum, TOTAL_HIST);
    scatterA_kernel<<<NT, 256, 0, stream>>>(row, col, tileHist, binned, N_EDGES);
    passB_kernel   <<<NBUCK, 1024, 0, stream>>>(tileHist, binned, offs, dis, csr, N_EDGES);
    xw1_kernel     <<<(N_NODES + 255) / 256, 256, 0, stream>>>(x, W1, dis, h1b);
    gather1_kernel <<<N_NODES / 16, 256, 0, stream>>>(offs, csr, h1b, b1, rs);
    gather2_pool_kernel<<<N_NODES / 16, 256, 0, stream>>>(offs, csr, rs, W2, batch, sums);
    pool_finish_kernel <<<1, 64, 0, stream>>>(sums, batch, b2, out);
}

// Round 7
// 411.259 us; speedup vs baseline: 2.0203x; 1.0972x over previous
//
#include <hip/hip_runtime.h>
#include <math.h>

#define N_NODES 200000
#define N_EDGES 6400000
#define F_IN    128
#define H_HID   6
#define C_OUT   10
#define G_BATCH 64

#define TILE_E     8192                                // edges per sort tile
#define NT         ((N_EDGES + TILE_E - 1) / TILE_E)   // 782 tiles
#define NBUCK      ((N_NODES + 1023) / 1024)           // 196 buckets of 1024 nodes
#define TOTAL_HIST (NBUCK * NT)                        // 153272
#define NSB        ((TOTAL_HIST + 255) / 256)          // 599 scan blocks
#define EPT        (TILE_E / 256)                      // 32 edges per thread
#define QCAP       10240                               // passB quarter staging (40 KB)

// ---- bf16 helpers (RNE) ---------------------------------------------------
__device__ __forceinline__ unsigned short f2bf(float f) {
    unsigned u = __float_as_uint(f);
    u += 0x7fff + ((u >> 16) & 1);
    return (unsigned short)(u >> 16);
}
__device__ __forceinline__ unsigned pack2(float a, float b) {
    return (unsigned)f2bf(a) | ((unsigned)f2bf(b) << 16);
}
__device__ __forceinline__ float bf_lo(unsigned u) { return __uint_as_float(u << 16); }
__device__ __forceinline__ float bf_hi(unsigned u) { return __uint_as_float(u & 0xffff0000u); }

// ---------------------------------------------------------------------------
// A1) per-tile histogram over destination buckets (col >> 10). LDS atomics only.
__global__ void histA_kernel(const int* __restrict__ col, int* __restrict__ tileHist, int E) {
    __shared__ int h[NBUCK];
    for (int i = threadIdx.x; i < NBUCK; i += 256) h[i] = 0;
    __syncthreads();
    int t = blockIdx.x;
    int base = t * TILE_E;
    for (int k = 0; k < TILE_E; k += 256) {
        int e = base + k + threadIdx.x;
        if (e < E) atomicAdd(&h[col[e] >> 10], 1);
    }
    __syncthreads();
    for (int b = threadIdx.x; b < NBUCK; b += 256) tileHist[b * NT + t] = h[b];
}

// A2) 3-phase exclusive scan over tileHist (bucket-major)
__global__ void scan_blocksum(const int* __restrict__ a, int* __restrict__ bsum, int n) {
    __shared__ int sm[256];
    int i = blockIdx.x * 256 + threadIdx.x;
    sm[threadIdx.x] = (i < n) ? a[i] : 0;
    __syncthreads();
    for (int s = 128; s > 0; s >>= 1) {
        if (threadIdx.x < s) sm[threadIdx.x] += sm[threadIdx.x + s];
        __syncthreads();
    }
    if (threadIdx.x == 0) bsum[blockIdx.x] = sm[0];
}

__global__ void scan_bsum(int* __restrict__ bsum, int nb) {
    int lane = threadIdx.x;   // block = 64
    int carry = 0;
    for (int base = 0; base < nb; base += 64) {
        int i = base + lane;
        int orig = (i < nb) ? bsum[i] : 0;
        int v = orig;
#pragma unroll
        for (int off = 1; off < 64; off <<= 1) {
            int t = __shfl_up(v, off);
            if (lane >= off) v += t;
        }
        int total = __shfl(v, 63);
        if (i < nb) bsum[i] = carry + v - orig;
        carry += total;
    }
}

__global__ void scan_final(int* __restrict__ a, const int* __restrict__ bsum, int n) {
    __shared__ int sm[256];
    int tid = threadIdx.x;
    int i = blockIdx.x * 256 + tid;
    int v = (i < n) ? a[i] : 0;
    sm[tid] = v;
    __syncthreads();
    for (int off = 1; off < 256; off <<= 1) {
        int t = (tid >= off) ? sm[tid - off] : 0;
        __syncthreads();
        sm[tid] += t;
        __syncthreads();
    }
    if (i < n) a[i] = sm[tid] - v + bsum[blockIdx.x];
}

// A3) scatter: LDS-sort the tile by bucket, streaming writes per run.
//     Payload packed: (col&1023)<<18 | row.
__global__ __launch_bounds__(256) void scatterA_kernel(const int* __restrict__ row,
                                                       const int* __restrict__ col,
                                                       const int* __restrict__ scanned,
                                                       int* __restrict__ binned, int E) {
    __shared__ int sortbuf[TILE_E];   // 32 KB
    __shared__ int cnt[256];
    __shared__ int pos[257];
    __shared__ int cur[256];
    __shared__ int lbase[NBUCK];
    int t = blockIdx.x, tid = threadIdx.x;
    int base = t * TILE_E;
    int tile_n = min(TILE_E, E - base);

    cnt[tid] = 0;
    if (tid < NBUCK) lbase[tid] = scanned[tid * NT + t];
    __syncthreads();

    int myval[EPT];
#pragma unroll
    for (int k = 0; k < EPT; ++k) {
        int e = base + k * 256 + tid;
        if (e < E) {
            int c = col[e];
            myval[k] = ((c & 1023) << 18) | row[e];
            atomicAdd(&cnt[c >> 10], 1);
        }
    }
    __syncthreads();

    int v = cnt[tid];
    pos[tid] = v;
    __syncthreads();
    for (int off = 1; off < 256; off <<= 1) {
        int tv = (tid >= off) ? pos[tid - off] : 0;
        __syncthreads();
        pos[tid] += tv;
        __syncthreads();
    }
    int incl = pos[tid];
    __syncthreads();
    pos[tid] = incl - v;
    cur[tid] = incl - v;
    if (tid == 255) pos[256] = incl;
    __syncthreads();

#pragma unroll
    for (int k = 0; k < EPT; ++k) {
        int e = base + k * 256 + tid;
        if (e < E) {
            int b = col[e] >> 10;
            int p = atomicAdd(&cur[b], 1);
            sortbuf[p] = myval[k];
        }
    }
    __syncthreads();

    for (int i = tid; i < tile_n; i += 256) {
        int lo = 0, hi = NBUCK - 1;
        while (lo < hi) {
            int mid = (lo + hi + 1) >> 1;
            if (pos[mid] <= i) lo = mid; else hi = mid - 1;
        }
        binned[lbase[lo] + (i - pos[lo])] = sortbuf[i];
    }
}

// B) passB v2: per-bucket CSR with LDS-staged QUARTER write-out (coalesced csr).
__global__ __launch_bounds__(1024) void passB_kernel(const int* __restrict__ scanned,
                                                     const int* __restrict__ binned,
                                                     int* __restrict__ offs, float* __restrict__ dis,
                                                     int* __restrict__ csr, int E) {
    __shared__ int cnt[1024];
    __shared__ int scn[1024];
    __shared__ int cur[256];
    __shared__ int sortbuf[QCAP];     // 40 KB
    int b = blockIdx.x, tid = threadIdx.x;
    int bb = scanned[b * NT];
    int be = (b + 1 < NBUCK) ? scanned[(b + 1) * NT] : E;
    cnt[tid] = 0;
    __syncthreads();
    // count (unrolled x4 for MLP)
    int e = bb + tid;
    for (; e + 3072 < be; e += 4096) {
        int p0 = binned[e], p1 = binned[e + 1024], p2 = binned[e + 2048], p3 = binned[e + 3072];
        atomicAdd(&cnt[p0 >> 18], 1); atomicAdd(&cnt[p1 >> 18], 1);
        atomicAdd(&cnt[p2 >> 18], 1); atomicAdd(&cnt[p3 >> 18], 1);
    }
    for (; e < be; e += 1024) atomicAdd(&cnt[binned[e] >> 18], 1);
    __syncthreads();
    int v = cnt[tid];
    scn[tid] = v;
    __syncthreads();
    for (int off = 1; off < 1024; off <<= 1) {
        int t2 = (tid >= off) ? scn[tid - off] : 0;
        __syncthreads();
        scn[tid] += t2;
        __syncthreads();
    }
    int excl = scn[tid] - v;
    scn[tid] = excl;                  // own-slot rewrite, no race
    int n = (b << 10) + tid;
    if (n < N_NODES) {
        offs[n] = bb + excl;
        dis[n] = rsqrtf((float)v + 1.0f);
    }
    if (b == NBUCK - 1 && tid == 0) offs[N_NODES] = E;
    __syncthreads();
    int total = be - bb;
#define PLACE(p) { int loc = (p) >> 18; if ((loc >> 8) == q) {                      \
        int ps = scn[loc] - qbase + atomicAdd(&cur[loc & 255], 1);                  \
        if (ps < QCAP) sortbuf[ps] = (p) & 0x3FFFF;                                 \
        else csr[bb + qbase + ps] = (p) & 0x3FFFF; } }
    for (int q = 0; q < 4; ++q) {
        int qbase = scn[q << 8];
        int qend = (q < 3) ? scn[(q + 1) << 8] : total;
        int qn = qend - qbase;
        if (tid < 256) cur[tid] = 0;
        __syncthreads();
        int e2 = bb + tid;
        for (; e2 + 3072 < be; e2 += 4096) {
            int p0 = binned[e2], p1 = binned[e2 + 1024], p2 = binned[e2 + 2048], p3 = binned[e2 + 3072];
            PLACE(p0) PLACE(p1) PLACE(p2) PLACE(p3)
        }
        for (; e2 < be; e2 += 1024) { int p = binned[e2]; PLACE(p) }
        __syncthreads();
        int lim = qn < QCAP ? qn : QCAP;
        for (int i = tid; i < lim; i += 1024) csr[bb + qbase + i] = sortbuf[i];
        __syncthreads();
    }
#undef PLACE
}

// ---------------------------------------------------------------------------
// xw1: h1b row (uint4) = { bf16(d*a0,d*a1), bf16(d*a2,d*a3), bf16(d*a4,d*a5), bits(d) }
__global__ void xw1_kernel(const float* __restrict__ x, const float* __restrict__ W1,
                           const float* __restrict__ dis, uint4* __restrict__ h1b) {
    __shared__ float w[F_IN * H_HID];
    for (int i = threadIdx.x; i < F_IN * H_HID; i += blockDim.x) w[i] = W1[i];
    __syncthreads();
    int n = blockIdx.x * blockDim.x + threadIdx.x;
    if (n >= N_NODES) return;
    float acc[H_HID] = {0.f, 0.f, 0.f, 0.f, 0.f, 0.f};
    const float4* xr = (const float4*)(x + (size_t)n * F_IN);
#pragma unroll 4
    for (int f4 = 0; f4 < F_IN / 4; ++f4) {
        float4 v = xr[f4];
        int f = f4 * 4;
#pragma unroll
        for (int j = 0; j < H_HID; ++j) {
            acc[j] += v.x * w[(f + 0) * H_HID + j] + v.y * w[(f + 1) * H_HID + j]
                    + v.z * w[(f + 2) * H_HID + j] + v.w * w[(f + 3) * H_HID + j];
        }
    }
    float d = dis[n];
    uint4 o;
    o.x = pack2(d * acc[0], d * acc[1]);
    o.y = pack2(d * acc[2], d * acc[3]);
    o.z = pack2(d * acc[4], d * acc[5]);
    o.w = __float_as_uint(d);
    h1b[n] = o;
}

// gather conv1 v2: 8 lanes/node, 4-deep unroll (4 gathers in flight per lane).
__global__ void gather1_kernel(const int* __restrict__ offs, const int* __restrict__ csr,
                               const uint4* __restrict__ h1b, const float* __restrict__ b1,
                               uint4* __restrict__ rs) {
    int grp = threadIdx.x >> 3, sub = threadIdx.x & 7;
    int n = blockIdx.x * 32 + grp;
    int s = offs[n], e_end = offs[n + 1];
    float a[H_HID] = {0.f, 0.f, 0.f, 0.f, 0.f, 0.f};
    int e = s + sub;
    for (; e + 24 < e_end; e += 32) {
        int i0 = csr[e], i1 = csr[e + 8], i2 = csr[e + 16], i3 = csr[e + 24];
        uint4 v0 = h1b[i0], v1 = h1b[i1], v2 = h1b[i2], v3 = h1b[i3];
        a[0] += (bf_lo(v0.x) + bf_lo(v1.x)) + (bf_lo(v2.x) + bf_lo(v3.x));
        a[1] += (bf_hi(v0.x) + bf_hi(v1.x)) + (bf_hi(v2.x) + bf_hi(v3.x));
        a[2] += (bf_lo(v0.y) + bf_lo(v1.y)) + (bf_lo(v2.y) + bf_lo(v3.y));
        a[3] += (bf_hi(v0.y) + bf_hi(v1.y)) + (bf_hi(v2.y) + bf_hi(v3.y));
        a[4] += (bf_lo(v0.z) + bf_lo(v1.z)) + (bf_lo(v2.z) + bf_lo(v3.z));
        a[5] += (bf_hi(v0.z) + bf_hi(v1.z)) + (bf_hi(v2.z) + bf_hi(v3.z));
    }
    for (; e < e_end; e += 8) {
        uint4 v = h1b[csr[e]];
        a[0] += bf_lo(v.x); a[1] += bf_hi(v.x);
        a[2] += bf_lo(v.y); a[3] += bf_hi(v.y);
        a[4] += bf_lo(v.z); a[5] += bf_hi(v.z);
    }
#pragma unroll
    for (int j = 0; j < H_HID; ++j)
#pragma unroll
        for (int off = 4; off > 0; off >>= 1) a[j] += __shfl_xor(a[j], off);
    uint4 self = h1b[n];
    float d = __uint_as_float(self.w);
    float sf[H_HID] = {bf_lo(self.x), bf_hi(self.x), bf_lo(self.y),
                       bf_hi(self.y), bf_lo(self.z), bf_hi(self.z)};
    if (sub == 0) {
        float r[H_HID];
#pragma unroll
        for (int j = 0; j < H_HID; ++j) {
            float vv = d * (a[j] + sf[j]) + b1[j];
            r[j] = d * (vv > 0.f ? vv : 0.f);    // pre-scaled for layer 2
        }
        uint4 o;
        o.x = pack2(r[0], r[1]);
        o.y = pack2(r[2], r[3]);
        o.z = pack2(r[4], r[5]);
        o.w = self.w;
        rs[n] = o;
    }
}

// gather conv2 v2 (6ch) + W2 post-aggregation + fused pooling. 8 lanes/node.
__global__ void gather2_pool_kernel(const int* __restrict__ offs, const int* __restrict__ csr,
                                    const uint4* __restrict__ rs, const float* __restrict__ W2,
                                    const int* __restrict__ batch, float* __restrict__ sums) {
    __shared__ float w2s[H_HID * C_OUT];
    __shared__ float nodeval[32][C_OUT];
    __shared__ int lg[32];
    if (threadIdx.x < H_HID * C_OUT) w2s[threadIdx.x] = W2[threadIdx.x];
    __syncthreads();
    int grp = threadIdx.x >> 3, sub = threadIdx.x & 7;
    int n = blockIdx.x * 32 + grp;
    int s = offs[n], e_end = offs[n + 1];
    float a[H_HID] = {0.f, 0.f, 0.f, 0.f, 0.f, 0.f};
    int e = s + sub;
    for (; e + 24 < e_end; e += 32) {
        int i0 = csr[e], i1 = csr[e + 8], i2 = csr[e + 16], i3 = csr[e + 24];
        uint4 v0 = rs[i0], v1 = rs[i1], v2 = rs[i2], v3 = rs[i3];
        a[0] += (bf_lo(v0.x) + bf_lo(v1.x)) + (bf_lo(v2.x) + bf_lo(v3.x));
        a[1] += (bf_hi(v0.x) + bf_hi(v1.x)) + (bf_hi(v2.x) + bf_hi(v3.x));
        a[2] += (bf_lo(v0.y) + bf_lo(v1.y)) + (bf_lo(v2.y) + bf_lo(v3.y));
        a[3] += (bf_hi(v0.y) + bf_hi(v1.y)) + (bf_hi(v2.y) + bf_hi(v3.y));
        a[4] += (bf_lo(v0.z) + bf_lo(v1.z)) + (bf_lo(v2.z) + bf_lo(v3.z));
        a[5] += (bf_hi(v0.z) + bf_hi(v1.z)) + (bf_hi(v2.z) + bf_hi(v3.z));
    }
    for (; e < e_end; e += 8) {
        uint4 v = rs[csr[e]];
        a[0] += bf_lo(v.x); a[1] += bf_hi(v.x);
        a[2] += bf_lo(v.y); a[3] += bf_hi(v.y);
        a[4] += bf_lo(v.z); a[5] += bf_hi(v.z);
    }
#pragma unroll
    for (int j = 0; j < H_HID; ++j)
#pragma unroll
        for (int off = 4; off > 0; off >>= 1) a[j] += __shfl_xor(a[j], off);
    uint4 self = rs[n];
    float d = __uint_as_float(self.w);
    float t[H_HID] = {a[0] + bf_lo(self.x), a[1] + bf_hi(self.x), a[2] + bf_lo(self.y),
                      a[3] + bf_hi(self.y), a[4] + bf_lo(self.z), a[5] + bf_hi(self.z)};
    {   // all 8 lanes hold the full sum after xor-reduce
        float acc = 0.f;
#pragma unroll
        for (int j = 0; j < H_HID; ++j) acc += t[j] * w2s[j * C_OUT + sub];
        nodeval[grp][sub] = d * acc;
        if (sub < 2) {
            float acc2 = 0.f;
#pragma unroll
            for (int j = 0; j < H_HID; ++j) acc2 += t[j] * w2s[j * C_OUT + sub + 8];
            nodeval[grp][sub + 8] = d * acc2;
        }
    }
    if (sub == 0) lg[grp] = batch[n];
    __syncthreads();
    if (threadIdx.x < C_OUT) {
        int c = threadIdx.x;
        float acc = 0.f;
        int gcur = lg[0];
#pragma unroll
        for (int w = 0; w < 32; ++w) {
            if (lg[w] != gcur) {
                atomicAdd(&sums[gcur * C_OUT + c], acc);
                gcur = lg[w]; acc = 0.f;
            }
            acc += nodeval[w][c];
        }
        atomicAdd(&sums[gcur * C_OUT + c], acc);
    }
}

// mean (counts via binary search on sorted batch) + b2 + log_softmax
__global__ void pool_finish_kernel(const float* __restrict__ sums, const int* __restrict__ batch,
                                   const float* __restrict__ b2, float* __restrict__ out) {
    int g = threadIdx.x;
    if (g >= G_BATCH) return;
    int lo = 0, hi = N_NODES;
    while (lo < hi) { int mid = (lo + hi) >> 1; if (batch[mid] < g) lo = mid + 1; else hi = mid; }
    int c0 = lo;
    hi = N_NODES;
    while (lo < hi) { int mid = (lo + hi) >> 1; if (batch[mid] < g + 1) lo = mid + 1; else hi = mid; }
    float inv = 1.0f / fmaxf((float)(lo - c0), 1.0f);
    float v[C_OUT], m = -INFINITY;
#pragma unroll
    for (int c = 0; c < C_OUT; ++c) {
        v[c] = sums[g * C_OUT + c] * inv + b2[c];
        m = fmaxf(m, v[c]);
    }
    float s = 0.f;
#pragma unroll
    for (int c = 0; c < C_OUT; ++c) s += expf(v[c] - m);
    float lse = m + logf(s);
#pragma unroll
    for (int c = 0; c < C_OUT; ++c) out[g * C_OUT + c] = v[c] - lse;
}

extern "C" void kernel_launch(void* const* d_in, const int* in_sizes, int n_in,
                              void* d_out, int out_size, void* d_ws, size_t ws_size,
                              hipStream_t stream) {
    const float* x   = (const float*)d_in[0];
    const int* ei    = (const int*)d_in[1];
    const int* row   = ei;
    const int* col   = ei + N_EDGES;
    const int* batch = (const int*)d_in[2];
    const float* W1  = (const float*)d_in[3];
    const float* b1  = (const float*)d_in[4];
    const float* W2  = (const float*)d_in[5];
    const float* b2  = (const float*)d_in[6];
    float* out = (float*)d_out;

    // workspace layout — every region size a multiple of 16 B so uint4 arrays stay aligned
    char* p = (char*)d_ws;
    float* sums     = (float*)p;  p += (size_t)G_BATCH * C_OUT * 4;      // [zero] 2560B
    int*   tileHist = (int*)p;    p += (size_t)TOTAL_HIST * 4;           // 613088B
    int*   bsum     = (int*)p;    p += (size_t)(NSB + 1) * 4;            // 2400B
    int*   offs     = (int*)p;    p += (size_t)(N_NODES + 4) * 4;        // 800016B
    float* dis      = (float*)p;  p += (size_t)N_NODES * 4;              // 800000B
    int*   csr      = (int*)p;    p += (size_t)N_EDGES * 4;              // 25.6MB
    int*   binned   = (int*)p;                                           // 25.6MB, dead after passB
    uint4* h1b      = (uint4*)binned;                                    // 3.2MB, aliases binned
    uint4* rs       = (uint4*)binned + N_NODES;                          // 3.2MB

    hipMemsetAsync(sums, 0, (size_t)G_BATCH * C_OUT * 4, stream);

    histA_kernel   <<<NT, 256, 0, stream>>>(col, tileHist, N_EDGES);
    scan_blocksum  <<<NSB, 256, 0, stream>>>(tileHist, bsum, TOTAL_HIST);
    scan_bsum      <<<1, 64, 0, stream>>>(bsum, NSB);
    scan_final     <<<NSB, 256, 0, stream>>>(tileHist, bsum, TOTAL_HIST);
    scatterA_kernel<<<NT, 256, 0, stream>>>(row, col, tileHist, binned, N_EDGES);
    passB_kernel   <<<NBUCK, 1024, 0, stream>>>(tileHist, binned, offs, dis, csr, N_EDGES);
    xw1_kernel     <<<(N_NODES + 255) / 256, 256, 0, stream>>>(x, W1, dis, h1b);
    gather1_kernel <<<N_NODES / 32, 256, 0, stream>>>(offs, csr, h1b, b1, rs);
    gather2_pool_kernel<<<N_NODES / 32, 256, 0, stream>>>(offs, csr, rs, W2, batch, sums);
    pool_finish_kernel <<<1, 64, 0, stream>>>(sums, batch, b2, out);
}

// Round 8
// 387.119 us; speedup vs baseline: 2.1463x; 1.0624x over previous
//
#include <hip/hip_runtime.h>
#include <math.h>

#define N_NODES 200000
#define N_EDGES 6400000
#define F_IN    128
#define H_HID   6
#define C_OUT   10
#define G_BATCH 64

#define TILE_E  16384                                // edges per sort tile
#define NT      ((N_EDGES + TILE_E - 1) / TILE_E)    // 391 tiles
#define NBUCK   ((N_NODES + 1023) / 1024)            // 196 buckets of 1024 nodes
#define BCAP    36864                                // fixed slots per bucket (mean 32768, +22 sigma)
#define EPT     (TILE_E / 512)                       // 32 edges per thread
#define QCAP    10240                                // passB quarter staging (40 KB)

// ---- bf16 helpers (RNE) ---------------------------------------------------
__device__ __forceinline__ unsigned short f2bf(float f) {
    unsigned u = __float_as_uint(f);
    u += 0x7fff + ((u >> 16) & 1);
    return (unsigned short)(u >> 16);
}
__device__ __forceinline__ unsigned pack2(float a, float b) {
    return (unsigned)f2bf(a) | ((unsigned)f2bf(b) << 16);
}
__device__ __forceinline__ float bf_lo(unsigned u) { return __uint_as_float(u << 16); }
__device__ __forceinline__ float bf_hi(unsigned u) { return __uint_as_float(u & 0xffff0000u); }

// ---------------------------------------------------------------------------
// A) scatter with on-the-fly reservation: LDS-sort tile by bucket, reserve each
//    bucket's run via ONE global atomic, stream runs into fixed bucket regions.
//    Payload packed: (col&1023)<<18 | row.
__global__ __launch_bounds__(512) void scatterA_kernel(const int* __restrict__ row,
                                                       const int* __restrict__ col,
                                                       int* __restrict__ gcur,
                                                       int* __restrict__ binned, int E) {
    __shared__ int sortbuf[TILE_E];   // 64 KB
    __shared__ int cnt[256];
    __shared__ int pos[257];
    __shared__ int cur[256];
    __shared__ int lbase[256];
    int t = blockIdx.x, tid = threadIdx.x;
    int base = t * TILE_E;
    int tile_n = min(TILE_E, E - base);

    if (tid < 256) cnt[tid] = 0;
    __syncthreads();

    // phase 0: read edges into registers, LDS histogram over buckets
    int myval[EPT];
#pragma unroll
    for (int k = 0; k < EPT; ++k) {
        int e = base + k * 512 + tid;
        if (e < E) {
            int c = col[e];
            myval[k] = ((c & 1023) << 18) | row[e];
            atomicAdd(&cnt[c >> 10], 1);
        }
    }
    __syncthreads();

    // phase 1: inclusive scan of cnt (first 256 threads), then exclusive + cursors
    if (tid < 256) pos[tid] = cnt[tid];
    __syncthreads();
    for (int off = 1; off < 256; off <<= 1) {
        int tv = (tid < 256 && tid >= off) ? pos[tid - off] : 0;
        __syncthreads();
        if (tid < 256) pos[tid] += tv;
        __syncthreads();
    }
    int incl = (tid < 256) ? pos[tid] : 0;
    __syncthreads();
    if (tid < 256) {
        int excl = incl - cnt[tid];
        pos[tid] = excl;
        cur[tid] = excl;
        if (tid == 255) pos[256] = incl;
        // reserve global space for this tile's run in bucket tid
        if (tid < NBUCK) {
            int c = cnt[tid];
            lbase[tid] = tid * BCAP + (c ? atomicAdd(&gcur[tid], c) : 0);
        }
    }
    __syncthreads();

    // phase 2: place into LDS sort buffer (col re-read is L1/L2-hot)
#pragma unroll
    for (int k = 0; k < EPT; ++k) {
        int e = base + k * 512 + tid;
        if (e < E) {
            int b = col[e] >> 10;
            int p = atomicAdd(&cur[b], 1);
            sortbuf[p] = myval[k];
        }
    }
    __syncthreads();

    // phase 3: streaming write-out; position -> bucket via LDS binary search
    for (int i = tid; i < tile_n; i += 512) {
        int lo = 0, hi = NBUCK - 1;
        while (lo < hi) {
            int mid = (lo + hi + 1) >> 1;
            if (pos[mid] <= i) lo = mid; else hi = mid - 1;
        }
        binned[lbase[lo] + (i - pos[lo])] = sortbuf[i];
    }
}

// B) per-bucket CSR with LDS-staged QUARTER write-out (coalesced csr).
__global__ __launch_bounds__(1024) void passB_kernel(const int* __restrict__ gcur,
                                                     const int* __restrict__ binned,
                                                     int* __restrict__ offs, int* __restrict__ endo,
                                                     float* __restrict__ dis,
                                                     int* __restrict__ csr, int E) {
    __shared__ int cnt[1024];
    __shared__ int scn[1024];
    __shared__ int cur[256];
    __shared__ int sortbuf[QCAP];     // 40 KB
    int b = blockIdx.x, tid = threadIdx.x;
    int bb = b * BCAP;
    int be = bb + gcur[b];
    cnt[tid] = 0;
    __syncthreads();
    // count (unrolled x4 for MLP)
    int e = bb + tid;
    for (; e + 3072 < be; e += 4096) {
        int p0 = binned[e], p1 = binned[e + 1024], p2 = binned[e + 2048], p3 = binned[e + 3072];
        atomicAdd(&cnt[p0 >> 18], 1); atomicAdd(&cnt[p1 >> 18], 1);
        atomicAdd(&cnt[p2 >> 18], 1); atomicAdd(&cnt[p3 >> 18], 1);
    }
    for (; e < be; e += 1024) atomicAdd(&cnt[binned[e] >> 18], 1);
    __syncthreads();
    int v = cnt[tid];
    scn[tid] = v;
    __syncthreads();
    for (int off = 1; off < 1024; off <<= 1) {
        int t2 = (tid >= off) ? scn[tid - off] : 0;
        __syncthreads();
        scn[tid] += t2;
        __syncthreads();
    }
    int excl = scn[tid] - v;
    scn[tid] = excl;                  // own-slot rewrite, no race
    int n = (b << 10) + tid;
    if (n < N_NODES) {
        offs[n] = bb + excl;
        endo[n] = bb + excl + v;
        dis[n] = rsqrtf((float)v + 1.0f);
    }
    __syncthreads();
    int total = be - bb;
#define PLACE(p) { int loc = (p) >> 18; if ((loc >> 8) == q) {                      \
        int ps = scn[loc] - qbase + atomicAdd(&cur[loc & 255], 1);                  \
        if (ps < QCAP) sortbuf[ps] = (p) & 0x3FFFF;                                 \
        else csr[bb + qbase + ps] = (p) & 0x3FFFF; } }
    for (int q = 0; q < 4; ++q) {
        int qbase = scn[q << 8];
        int qend = (q < 3) ? scn[(q + 1) << 8] : total;
        int qn = qend - qbase;
        if (tid < 256) cur[tid] = 0;
        __syncthreads();
        int e2 = bb + tid;
        for (; e2 + 3072 < be; e2 += 4096) {
            int p0 = binned[e2], p1 = binned[e2 + 1024], p2 = binned[e2 + 2048], p3 = binned[e2 + 3072];
            PLACE(p0) PLACE(p1) PLACE(p2) PLACE(p3)
        }
        for (; e2 < be; e2 += 1024) { int p = binned[e2]; PLACE(p) }
        __syncthreads();
        int lim = qn < QCAP ? qn : QCAP;
        for (int i = tid; i < lim; i += 1024) csr[bb + qbase + i] = sortbuf[i];
        __syncthreads();
    }
#undef PLACE
}

// ---------------------------------------------------------------------------
// xw1: h1b row (uint4) = { bf16(d*a0,d*a1), bf16(d*a2,d*a3), bf16(d*a4,d*a5), bits(d) }
__global__ void xw1_kernel(const float* __restrict__ x, const float* __restrict__ W1,
                           const float* __restrict__ dis, uint4* __restrict__ h1b) {
    __shared__ float w[F_IN * H_HID];
    for (int i = threadIdx.x; i < F_IN * H_HID; i += blockDim.x) w[i] = W1[i];
    __syncthreads();
    int n = blockIdx.x * blockDim.x + threadIdx.x;
    if (n >= N_NODES) return;
    float acc[H_HID] = {0.f, 0.f, 0.f, 0.f, 0.f, 0.f};
    const float4* xr = (const float4*)(x + (size_t)n * F_IN);
#pragma unroll 4
    for (int f4 = 0; f4 < F_IN / 4; ++f4) {
        float4 v = xr[f4];
        int f = f4 * 4;
#pragma unroll
        for (int j = 0; j < H_HID; ++j) {
            acc[j] += v.x * w[(f + 0) * H_HID + j] + v.y * w[(f + 1) * H_HID + j]
                    + v.z * w[(f + 2) * H_HID + j] + v.w * w[(f + 3) * H_HID + j];
        }
    }
    float d = dis[n];
    uint4 o;
    o.x = pack2(d * acc[0], d * acc[1]);
    o.y = pack2(d * acc[2], d * acc[3]);
    o.z = pack2(d * acc[4], d * acc[5]);
    o.w = __float_as_uint(d);
    h1b[n] = o;
}

// gather conv1: 8 lanes/node, 4-deep unroll (4 gathers in flight per lane).
__global__ void gather1_kernel(const int* __restrict__ offs, const int* __restrict__ endo,
                               const int* __restrict__ csr,
                               const uint4* __restrict__ h1b, const float* __restrict__ b1,
                               uint4* __restrict__ rs) {
    int grp = threadIdx.x >> 3, sub = threadIdx.x & 7;
    int n = blockIdx.x * 32 + grp;
    int s = offs[n], e_end = endo[n];
    float a[H_HID] = {0.f, 0.f, 0.f, 0.f, 0.f, 0.f};
    int e = s + sub;
    for (; e + 24 < e_end; e += 32) {
        int i0 = csr[e], i1 = csr[e + 8], i2 = csr[e + 16], i3 = csr[e + 24];
        uint4 v0 = h1b[i0], v1 = h1b[i1], v2 = h1b[i2], v3 = h1b[i3];
        a[0] += (bf_lo(v0.x) + bf_lo(v1.x)) + (bf_lo(v2.x) + bf_lo(v3.x));
        a[1] += (bf_hi(v0.x) + bf_hi(v1.x)) + (bf_hi(v2.x) + bf_hi(v3.x));
        a[2] += (bf_lo(v0.y) + bf_lo(v1.y)) + (bf_lo(v2.y) + bf_lo(v3.y));
        a[3] += (bf_hi(v0.y) + bf_hi(v1.y)) + (bf_hi(v2.y) + bf_hi(v3.y));
        a[4] += (bf_lo(v0.z) + bf_lo(v1.z)) + (bf_lo(v2.z) + bf_lo(v3.z));
        a[5] += (bf_hi(v0.z) + bf_hi(v1.z)) + (bf_hi(v2.z) + bf_hi(v3.z));
    }
    for (; e < e_end; e += 8) {
        uint4 v = h1b[csr[e]];
        a[0] += bf_lo(v.x); a[1] += bf_hi(v.x);
        a[2] += bf_lo(v.y); a[3] += bf_hi(v.y);
        a[4] += bf_lo(v.z); a[5] += bf_hi(v.z);
    }
#pragma unroll
    for (int j = 0; j < H_HID; ++j)
#pragma unroll
        for (int off = 4; off > 0; off >>= 1) a[j] += __shfl_xor(a[j], off);
    uint4 self = h1b[n];
    float d = __uint_as_float(self.w);
    float sf[H_HID] = {bf_lo(self.x), bf_hi(self.x), bf_lo(self.y),
                       bf_hi(self.y), bf_lo(self.z), bf_hi(self.z)};
    if (sub == 0) {
        float r[H_HID];
#pragma unroll
        for (int j = 0; j < H_HID; ++j) {
            float vv = d * (a[j] + sf[j]) + b1[j];
            r[j] = d * (vv > 0.f ? vv : 0.f);    // pre-scaled for layer 2
        }
        uint4 o;
        o.x = pack2(r[0], r[1]);
        o.y = pack2(r[2], r[3]);
        o.z = pack2(r[4], r[5]);
        o.w = self.w;
        rs[n] = o;
    }
}

// gather conv2 (6ch) + W2 post-aggregation + fused pooling. 8 lanes/node.
__global__ void gather2_pool_kernel(const int* __restrict__ offs, const int* __restrict__ endo,
                                    const int* __restrict__ csr,
                                    const uint4* __restrict__ rs, const float* __restrict__ W2,
                                    const int* __restrict__ batch, float* __restrict__ sums) {
    __shared__ float w2s[H_HID * C_OUT];
    __shared__ float nodeval[32][C_OUT];
    __shared__ int lg[32];
    if (threadIdx.x < H_HID * C_OUT) w2s[threadIdx.x] = W2[threadIdx.x];
    __syncthreads();
    int grp = threadIdx.x >> 3, sub = threadIdx.x & 7;
    int n = blockIdx.x * 32 + grp;
    int s = offs[n], e_end = endo[n];
    float a[H_HID] = {0.f, 0.f, 0.f, 0.f, 0.f, 0.f};
    int e = s + sub;
    for (; e + 24 < e_end; e += 32) {
        int i0 = csr[e], i1 = csr[e + 8], i2 = csr[e + 16], i3 = csr[e + 24];
        uint4 v0 = rs[i0], v1 = rs[i1], v2 = rs[i2], v3 = rs[i3];
        a[0] += (bf_lo(v0.x) + bf_lo(v1.x)) + (bf_lo(v2.x) + bf_lo(v3.x));
        a[1] += (bf_hi(v0.x) + bf_hi(v1.x)) + (bf_hi(v2.x) + bf_hi(v3.x));
        a[2] += (bf_lo(v0.y) + bf_lo(v1.y)) + (bf_lo(v2.y) + bf_lo(v3.y));
        a[3] += (bf_hi(v0.y) + bf_hi(v1.y)) + (bf_hi(v2.y) + bf_hi(v3.y));
        a[4] += (bf_lo(v0.z) + bf_lo(v1.z)) + (bf_lo(v2.z) + bf_lo(v3.z));
        a[5] += (bf_hi(v0.z) + bf_hi(v1.z)) + (bf_hi(v2.z) + bf_hi(v3.z));
    }
    for (; e < e_end; e += 8) {
        uint4 v = rs[csr[e]];
        a[0] += bf_lo(v.x); a[1] += bf_hi(v.x);
        a[2] += bf_lo(v.y); a[3] += bf_hi(v.y);
        a[4] += bf_lo(v.z); a[5] += bf_hi(v.z);
    }
#pragma unroll
    for (int j = 0; j < H_HID; ++j)
#pragma unroll
        for (int off = 4; off > 0; off >>= 1) a[j] += __shfl_xor(a[j], off);
    uint4 self = rs[n];
    float d = __uint_as_float(self.w);
    float t[H_HID] = {a[0] + bf_lo(self.x), a[1] + bf_hi(self.x), a[2] + bf_lo(self.y),
                      a[3] + bf_hi(self.y), a[4] + bf_lo(self.z), a[5] + bf_hi(self.z)};
    {   // all 8 lanes hold the full sum after xor-reduce
        float acc = 0.f;
#pragma unroll
        for (int j = 0; j < H_HID; ++j) acc += t[j] * w2s[j * C_OUT + sub];
        nodeval[grp][sub] = d * acc;
        if (sub < 2) {
            float acc2 = 0.f;
#pragma unroll
            for (int j = 0; j < H_HID; ++j) acc2 += t[j] * w2s[j * C_OUT + sub + 8];
            nodeval[grp][sub + 8] = d * acc2;
        }
    }
    if (sub == 0) lg[grp] = batch[n];
    __syncthreads();
    if (threadIdx.x < C_OUT) {
        int c = threadIdx.x;
        float acc = 0.f;
        int gcur2 = lg[0];
#pragma unroll
        for (int w = 0; w < 32; ++w) {
            if (lg[w] != gcur2) {
                atomicAdd(&sums[gcur2 * C_OUT + c], acc);
                gcur2 = lg[w]; acc = 0.f;
            }
            acc += nodeval[w][c];
        }
        atomicAdd(&sums[gcur2 * C_OUT + c], acc);
    }
}

// mean (counts via binary search on sorted batch) + b2 + log_softmax
__global__ void pool_finish_kernel(const float* __restrict__ sums, const int* __restrict__ batch,
                                   const float* __restrict__ b2, float* __restrict__ out) {
    int g = threadIdx.x;
    if (g >= G_BATCH) return;
    int lo = 0, hi = N_NODES;
    while (lo < hi) { int mid = (lo + hi) >> 1; if (batch[mid] < g) lo = mid + 1; else hi = mid; }
    int c0 = lo;
    hi = N_NODES;
    while (lo < hi) { int mid = (lo + hi) >> 1; if (batch[mid] < g + 1) lo = mid + 1; else hi = mid; }
    float inv = 1.0f / fmaxf((float)(lo - c0), 1.0f);
    float v[C_OUT], m = -INFINITY;
#pragma unroll
    for (int c = 0; c < C_OUT; ++c) {
        v[c] = sums[g * C_OUT + c] * inv + b2[c];
        m = fmaxf(m, v[c]);
    }
    float s = 0.f;
#pragma unroll
    for (int c = 0; c < C_OUT; ++c) s += expf(v[c] - m);
    float lse = m + logf(s);
#pragma unroll
    for (int c = 0; c < C_OUT; ++c) out[g * C_OUT + c] = v[c] - lse;
}

extern "C" void kernel_launch(void* const* d_in, const int* in_sizes, int n_in,
                              void* d_out, int out_size, void* d_ws, size_t ws_size,
                              hipStream_t stream) {
    const float* x   = (const float*)d_in[0];
    const int* ei    = (const int*)d_in[1];
    const int* row   = ei;
    const int* col   = ei + N_EDGES;
    const int* batch = (const int*)d_in[2];
    const float* W1  = (const float*)d_in[3];
    const float* b1  = (const float*)d_in[4];
    const float* W2  = (const float*)d_in[5];
    const float* b2  = (const float*)d_in[6];
    float* out = (float*)d_out;

    // workspace layout — region sizes multiples of 16 B so uint4 arrays stay aligned
    char* p = (char*)d_ws;
    float* sums   = (float*)p;  p += (size_t)G_BATCH * C_OUT * 4;       // [zero] 2560B
    int*   gcur   = (int*)p;    p += (size_t)200 * 4;                   // [zero] 800B (196 used)
    int*   offs   = (int*)p;    p += (size_t)N_NODES * 4;               // 800000B
    int*   endo   = (int*)p;    p += (size_t)N_NODES * 4;               // 800000B
    float* dis    = (float*)p;  p += (size_t)N_NODES * 4;               // 800000B
    int*   csr    = (int*)p;    p += (size_t)NBUCK * BCAP * 4;          // 28.9MB (gapped layout)
    int*   binned = (int*)p;                                            // 28.9MB, dead after passB
    uint4* h1b    = (uint4*)binned;                                     // 3.2MB, aliases binned
    uint4* rs     = (uint4*)binned + N_NODES;                           // 3.2MB

    hipMemsetAsync(sums, 0, (size_t)G_BATCH * C_OUT * 4 + 200 * 4, stream);   // sums + gcur

    scatterA_kernel<<<NT, 512, 0, stream>>>(row, col, gcur, binned, N_EDGES);
    passB_kernel   <<<NBUCK, 1024, 0, stream>>>(gcur, binned, offs, endo, dis, csr, N_EDGES);
    xw1_kernel     <<<(N_NODES + 255) / 256, 256, 0, stream>>>(x, W1, dis, h1b);
    gather1_kernel <<<N_NODES / 32, 256, 0, stream>>>(offs, endo, csr, h1b, b1, rs);
    gather2_pool_kernel<<<N_NODES / 32, 256, 0, stream>>>(offs, endo, csr, rs, W2, batch, sums);
    pool_finish_kernel <<<1, 64, 0, stream>>>(sums, batch, b2, out);
}